// Round 1
// baseline (1170.746 us; speedup 1.0000x reference)
//
#include <hip/hip_runtime.h>

#define NN 50000
#define NE 800000

typedef __bf16 bf16x8 __attribute__((ext_vector_type(8)));
typedef float f32x16 __attribute__((ext_vector_type(16)));

union U4 { unsigned u[4]; bf16x8 v; };

__device__ __forceinline__ unsigned pk2(float a, float b) {
  unsigned ua = __float_as_uint(a);
  unsigned ub = __float_as_uint(b);
  unsigned ra = (ua + 0x7FFFu + ((ua >> 16) & 1u)) >> 16;
  unsigned rb = (ub + 0x7FFFu + ((ub >> 16) & 1u)) & 0xFFFF0000u;
  return ra | rb;
}

extern "C" __global__ void __launch_bounds__(256)
edge_mlp_kernel(const float* __restrict__ x, const float* __restrict__ ew,
                const int* __restrict__ ei, const float* __restrict__ w1,
                const float* __restrict__ w2, const float* __restrict__ w3,
                const float* __restrict__ g1, const float* __restrict__ b1,
                const float* __restrict__ g2, const float* __restrict__ b2,
                const float* __restrict__ g3, const float* __restrict__ b3,
                unsigned* __restrict__ agg) {
  __shared__ unsigned lds_w[8192];  // 32 frags x 64 lanes x 16B = 32 KB
  const int tid = threadIdx.x;

  // ---- stage w1 (16 frags): slot j <-> k = 16t + 8g + j ----
  #pragma unroll 1
  for (int s = tid; s < 1024; s += 256) {
    const int F = s >> 6, L = s & 63;
    const int t = F >> 1, mt = F & 1;
    const int gg = L >> 5, o = (L & 31) + 32 * mt;
    const float* p = w1 + o * 128 + 16 * t + 8 * gg;
    unsigned* d = &lds_w[(unsigned)(F * 64 + L) * 4u];
    d[0] = pk2(p[0], p[1]); d[1] = pk2(p[2], p[3]);
    d[2] = pk2(p[4], p[5]); d[3] = pk2(p[6], p[7]);
  }
  // ---- stage w2/w3 (8 frags each): slot j <-> k = 16t + 4g + (j&3) + 8*(j>>2) ----
  #pragma unroll 1
  for (int s = tid; s < 1024; s += 256) {
    const int which = s >> 9, r = s & 511;
    const int F = r >> 6, L = r & 63;
    const int t = F >> 1, mt = F & 1;
    const int gg = L >> 5, o = (L & 31) + 32 * mt;
    const float* W = which ? w3 : w2;
    const float* p = W + o * 64 + 16 * t + 4 * gg;
    unsigned* d = &lds_w[(unsigned)((16 + which * 8 + F) * 64 + L) * 4u];
    d[0] = pk2(p[0], p[1]); d[1] = pk2(p[2], p[3]);
    d[2] = pk2(p[8], p[9]); d[3] = pk2(p[10], p[11]);
  }
  __syncthreads();

  const int lane = tid & 63;
  const int el = lane & 31;
  const int g = lane >> 5;
  const bf16x8* wfrag = (const bf16x8*)lds_w;

  const int wid = blockIdx.x * 4 + (tid >> 6);
  const int nw = gridDim.x * 4;

  for (int tile = wid; tile < (NE / 32); tile += nw) {
    const int e = tile * 32 + el;
    int vsrc = ei[e];
    int vtgt = ei[NE + e];
    // crash-guard clamp (indices should already be in [0,NN))
    vsrc = min(max(vsrc, 0), NN - 1);
    vtgt = min(max(vtgt, 0), NN - 1);
    const float wgt = ew[e];

    const float* xi = x + (size_t)vtgt * 64 + 8 * g;
    const float* xj = x + (size_t)vsrc * 64 + 8 * g;

    // ---- build m half-row: slots t=0..3 -> x_i chunks, t=4..7 -> ew*(x_j-x_i) ----
    float m[64];
    #pragma unroll
    for (int t = 0; t < 4; ++t) {
      float4 a = *(const float4*)(xi + 16 * t);
      float4 b = *(const float4*)(xi + 16 * t + 4);
      float4 c = *(const float4*)(xj + 16 * t);
      float4 d4 = *(const float4*)(xj + 16 * t + 4);
      m[8*t+0] = a.x; m[8*t+1] = a.y; m[8*t+2] = a.z; m[8*t+3] = a.w;
      m[8*t+4] = b.x; m[8*t+5] = b.y; m[8*t+6] = b.z; m[8*t+7] = b.w;
      m[32+8*t+0] = wgt * (c.x - a.x);  m[32+8*t+1] = wgt * (c.y - a.y);
      m[32+8*t+2] = wgt * (c.z - a.z);  m[32+8*t+3] = wgt * (c.w - a.w);
      m[32+8*t+4] = wgt * (d4.x - b.x); m[32+8*t+5] = wgt * (d4.y - b.y);
      m[32+8*t+6] = wgt * (d4.z - b.z); m[32+8*t+7] = wgt * (d4.w - b.w);
    }

    // ---- LN1 stats over 128 (two lanes per edge) ----
    float sum = 0.f, ssq = 0.f;
    #pragma unroll
    for (int i = 0; i < 64; ++i) { sum += m[i]; ssq += m[i] * m[i]; }
    sum += __shfl_xor(sum, 32);
    ssq += __shfl_xor(ssq, 32);
    const float mean1 = sum * (1.f / 128.f);
    const float rstd1 = rsqrtf(ssq * (1.f / 128.f) - mean1 * mean1 + 1e-5f);
    const float c01 = -mean1 * rstd1;

    // ---- normalize + affine + LeakyReLU + pack B1 frags ----
    U4 B1[8];
    #pragma unroll
    for (int t = 0; t < 8; ++t) {
      const int kb = (t < 4) ? (16 * t + 8 * g) : (64 + 16 * (t - 4) + 8 * g);
      float4 ga = *(const float4*)(g1 + kb);
      float4 gb = *(const float4*)(g1 + kb + 4);
      float4 ba = *(const float4*)(b1 + kb);
      float4 bb = *(const float4*)(b1 + kb + 4);
      float ggv[8] = {ga.x, ga.y, ga.z, ga.w, gb.x, gb.y, gb.z, gb.w};
      float bbv[8] = {ba.x, ba.y, ba.z, ba.w, bb.x, bb.y, bb.z, bb.w};
      float h[8];
      #pragma unroll
      for (int j = 0; j < 8; ++j) {
        float v = fmaf(m[8 * t + j], rstd1, c01);
        v = fmaf(v, ggv[j], bbv[j]);
        h[j] = v > 0.f ? v : 0.2f * v;
      }
      B1[t].u[0] = pk2(h[0], h[1]); B1[t].u[1] = pk2(h[2], h[3]);
      B1[t].u[2] = pk2(h[4], h[5]); B1[t].u[3] = pk2(h[6], h[7]);
    }

    // ---- stage 1: C' = w1 @ h1^T  (64x32) ----
    f32x16 C0, C1;
    #pragma unroll
    for (int i = 0; i < 16; ++i) { C0[i] = 0.f; C1[i] = 0.f; }
    #pragma unroll
    for (int t = 0; t < 8; ++t) {
      C0 = __builtin_amdgcn_mfma_f32_32x32x16_bf16(wfrag[(2 * t + 0) * 64 + lane], B1[t].v, C0, 0, 0, 0);
      C1 = __builtin_amdgcn_mfma_f32_32x32x16_bf16(wfrag[(2 * t + 1) * 64 + lane], B1[t].v, C1, 0, 0, 0);
    }

    // ---- LN2 (+affine+act) -> B2 frags ----
    float s2 = 0.f, q2 = 0.f;
    #pragma unroll
    for (int i = 0; i < 16; ++i) {
      s2 += C0[i] + C1[i];
      q2 += C0[i] * C0[i] + C1[i] * C1[i];
    }
    s2 += __shfl_xor(s2, 32); q2 += __shfl_xor(q2, 32);
    const float mean2 = s2 * (1.f / 64.f);
    const float rstd2 = rsqrtf(q2 * (1.f / 64.f) - mean2 * mean2 + 1e-5f);
    const float c02 = -mean2 * rstd2;

    float h2[32];
    #pragma unroll
    for (int mt = 0; mt < 2; ++mt) {
      #pragma unroll
      for (int q = 0; q < 4; ++q) {
        const int f0 = 32 * mt + 8 * q + 4 * g;
        float4 gg4 = *(const float4*)(g2 + f0);
        float4 bb4 = *(const float4*)(b2 + f0);
        float ggv[4] = {gg4.x, gg4.y, gg4.z, gg4.w};
        float bbv[4] = {bb4.x, bb4.y, bb4.z, bb4.w};
        #pragma unroll
        for (int r = 0; r < 4; ++r) {
          float v = mt ? C1[4 * q + r] : C0[4 * q + r];
          v = fmaf(v, rstd2, c02);
          v = fmaf(v, ggv[r], bbv[r]);
          h2[mt * 16 + 4 * q + r] = v > 0.f ? v : 0.2f * v;
        }
      }
    }
    U4 B2[4];
    #pragma unroll
    for (int t2 = 0; t2 < 4; ++t2) {
      const int base = (t2 >> 1) * 16 + (t2 & 1) * 8;
      B2[t2].u[0] = pk2(h2[base + 0], h2[base + 1]);
      B2[t2].u[1] = pk2(h2[base + 2], h2[base + 3]);
      B2[t2].u[2] = pk2(h2[base + 4], h2[base + 5]);
      B2[t2].u[3] = pk2(h2[base + 6], h2[base + 7]);
    }

    // ---- stage 2 ----
    f32x16 D0, D1;
    #pragma unroll
    for (int i = 0; i < 16; ++i) { D0[i] = 0.f; D1[i] = 0.f; }
    #pragma unroll
    for (int t2 = 0; t2 < 4; ++t2) {
      D0 = __builtin_amdgcn_mfma_f32_32x32x16_bf16(wfrag[(16 + 2 * t2 + 0) * 64 + lane], B2[t2].v, D0, 0, 0, 0);
      D1 = __builtin_amdgcn_mfma_f32_32x32x16_bf16(wfrag[(16 + 2 * t2 + 1) * 64 + lane], B2[t2].v, D1, 0, 0, 0);
    }

    // ---- LN3 (+affine+act) -> B3 frags ----
    float s3 = 0.f, q3 = 0.f;
    #pragma unroll
    for (int i = 0; i < 16; ++i) {
      s3 += D0[i] + D1[i];
      q3 += D0[i] * D0[i] + D1[i] * D1[i];
    }
    s3 += __shfl_xor(s3, 32); q3 += __shfl_xor(q3, 32);
    const float mean3 = s3 * (1.f / 64.f);
    const float rstd3 = rsqrtf(q3 * (1.f / 64.f) - mean3 * mean3 + 1e-5f);
    const float c03 = -mean3 * rstd3;

    float h3[32];
    #pragma unroll
    for (int mt = 0; mt < 2; ++mt) {
      #pragma unroll
      for (int q = 0; q < 4; ++q) {
        const int f0 = 32 * mt + 8 * q + 4 * g;
        float4 gg4 = *(const float4*)(g3 + f0);
        float4 bb4 = *(const float4*)(b3 + f0);
        float ggv[4] = {gg4.x, gg4.y, gg4.z, gg4.w};
        float bbv[4] = {bb4.x, bb4.y, bb4.z, bb4.w};
        #pragma unroll
        for (int r = 0; r < 4; ++r) {
          float v = mt ? D1[4 * q + r] : D0[4 * q + r];
          v = fmaf(v, rstd3, c03);
          v = fmaf(v, ggv[r], bbv[r]);
          h3[mt * 16 + 4 * q + r] = v > 0.f ? v : 0.2f * v;
        }
      }
    }
    U4 B3[4];
    #pragma unroll
    for (int t2 = 0; t2 < 4; ++t2) {
      const int base = (t2 >> 1) * 16 + (t2 & 1) * 8;
      B3[t2].u[0] = pk2(h3[base + 0], h3[base + 1]);
      B3[t2].u[1] = pk2(h3[base + 2], h3[base + 3]);
      B3[t2].u[2] = pk2(h3[base + 4], h3[base + 5]);
      B3[t2].u[3] = pk2(h3[base + 6], h3[base + 7]);
    }

    // ---- stage 3 ----
    f32x16 F0, F1;
    #pragma unroll
    for (int i = 0; i < 16; ++i) { F0[i] = 0.f; F1[i] = 0.f; }
    #pragma unroll
    for (int t2 = 0; t2 < 4; ++t2) {
      F0 = __builtin_amdgcn_mfma_f32_32x32x16_bf16(wfrag[(24 + 2 * t2 + 0) * 64 + lane], B3[t2].v, F0, 0, 0, 0);
      F1 = __builtin_amdgcn_mfma_f32_32x32x16_bf16(wfrag[(24 + 2 * t2 + 1) * 64 + lane], B3[t2].v, F1, 0, 0, 0);
    }

    // ---- atomic max scatter (monotone key encoding) ----
    unsigned* ap = agg + (size_t)vtgt * 64;
    #pragma unroll
    for (int mt = 0; mt < 2; ++mt) {
      #pragma unroll
      for (int reg = 0; reg < 16; ++reg) {
        const int f = (reg & 3) + 8 * (reg >> 2) + 4 * g + 32 * mt;
        float v = mt ? F1[reg] : F0[reg];
        unsigned u = __float_as_uint(v);
        unsigned key = (u & 0x80000000u) ? ~u : (u | 0x80000000u);
        atomicMax(ap + f, key);
      }
    }
  }
}

extern "C" __global__ void __launch_bounds__(256)
finalize_kernel(const float* __restrict__ x, unsigned* __restrict__ out) {
  const int i = blockIdx.x * 256 + threadIdx.x;
  if (i < NN * 64) {
    const unsigned key = out[i];
    const unsigned u = (key & 0x80000000u) ? (key & 0x7FFFFFFFu) : ~key;
    float v = __uint_as_float(u);
    if (((u >> 23) & 0xFFu) == 0xFFu) v = 0.f;  // sentinel / non-finite -> 0
    ((float*)out)[i] = v + x[i];
  }
}

extern "C" void kernel_launch(void* const* d_in, const int* in_sizes, int n_in,
                              void* d_out, int out_size, void* d_ws, size_t ws_size,
                              hipStream_t stream) {
  (void)in_sizes; (void)n_in; (void)d_ws; (void)ws_size; (void)out_size;
  const float* x  = (const float*)d_in[0];
  const float* ew = (const float*)d_in[1];
  const int*   ei = (const int*)d_in[2];
  const float* w1 = (const float*)d_in[3];
  const float* w2 = (const float*)d_in[4];
  const float* w3 = (const float*)d_in[5];
  const float* g1 = (const float*)d_in[6];
  const float* b1 = (const float*)d_in[7];
  const float* g2 = (const float*)d_in[8];
  const float* b2 = (const float*)d_in[9];
  const float* g3 = (const float*)d_in[10];
  const float* b3 = (const float*)d_in[11];
  unsigned* agg = (unsigned*)d_out;

  hipMemsetAsync(d_out, 0, (size_t)NN * 64 * sizeof(float), stream);
  edge_mlp_kernel<<<1024, 256, 0, stream>>>(x, ew, ei, w1, w2, w3,
                                            g1, b1, g2, b2, g3, b3, agg);
  finalize_kernel<<<(NN * 64 + 255) / 256, 256, 0, stream>>>(x, agg);
}

// Round 3
// 360.548 us; speedup vs baseline: 3.2471x; 3.2471x over previous
//
#include <hip/hip_runtime.h>
#include <math.h>

#define NN 50000
#define NE 800000

// workspace layout (two-pass path)
#define CNT_OFF    0u            // 50000 u32 counters (200 KB)
#define BUCKET_OFF (1u << 18)    // 50000*64 u32 edge ids (12.8 MB)
#define M_OFF      (1u << 24)    // 800000*64 bf16 edge outputs (102.4 MB)
#define WS_NEEDED  ((size_t)(1u << 24) + (size_t)NE * 64u * 2u)

typedef __bf16 bf16x8 __attribute__((ext_vector_type(8)));
typedef float f32x16 __attribute__((ext_vector_type(16)));

union U4 { unsigned u[4]; bf16x8 v; };

__device__ __forceinline__ unsigned pk2(float a, float b) {
  unsigned ua = __float_as_uint(a);
  unsigned ub = __float_as_uint(b);
  unsigned ra = (ua + 0x7FFFu + ((ua >> 16) & 1u)) >> 16;
  unsigned rb = (ub + 0x7FFFu + ((ub >> 16) & 1u)) & 0xFFFF0000u;
  return ra | rb;
}

// ---- pass 1: bucket-build scatter ----
extern "C" __global__ void __launch_bounds__(256)
scatter_kernel(const int* __restrict__ ei, unsigned* __restrict__ cnt,
               unsigned* __restrict__ bucket) {
  const int e = blockIdx.x * 256 + threadIdx.x;
  if (e < NE) {
    int t = ei[NE + e];
    t = min(max(t, 0), NN - 1);
    const unsigned p = atomicAdd(cnt + t, 1u);
    if (p < 64u) bucket[((unsigned)t << 6) + p] = (unsigned)e;
  }
}

// ---- pass 2: per-edge MLP (MFMA); epilogue = bf16 store OR atomic fallback ----
extern "C" __global__ void __launch_bounds__(256)
edge_mlp_kernel(const float* __restrict__ x, const float* __restrict__ ew,
                const int* __restrict__ ei, const float* __restrict__ w1,
                const float* __restrict__ w2, const float* __restrict__ w3,
                const float* __restrict__ g1, const float* __restrict__ b1,
                const float* __restrict__ g2, const float* __restrict__ b2,
                const float* __restrict__ g3, const float* __restrict__ b3,
                unsigned* __restrict__ agg /* may be null */,
                unsigned short* __restrict__ mbuf /* may be null */) {
  __shared__ unsigned lds_w[8192];  // 32 frags x 64 lanes x 16B = 32 KB
  const int tid = threadIdx.x;

  // ---- stage w1 (16 frags): slot j <-> k = 16t + 8g + j ----
  #pragma unroll 1
  for (int s = tid; s < 1024; s += 256) {
    const int F = s >> 6, L = s & 63;
    const int t = F >> 1, mt = F & 1;
    const int gg = L >> 5, o = (L & 31) + 32 * mt;
    const float* p = w1 + o * 128 + 16 * t + 8 * gg;
    unsigned* d = &lds_w[(unsigned)(F * 64 + L) * 4u];
    d[0] = pk2(p[0], p[1]); d[1] = pk2(p[2], p[3]);
    d[2] = pk2(p[4], p[5]); d[3] = pk2(p[6], p[7]);
  }
  // ---- stage w2/w3 (8 frags each): slot j <-> k = 16t + 4g + (j&3) + 8*(j>>2) ----
  #pragma unroll 1
  for (int s = tid; s < 1024; s += 256) {
    const int which = s >> 9, r = s & 511;
    const int F = r >> 6, L = r & 63;
    const int t = F >> 1, mt = F & 1;
    const int gg = L >> 5, o = (L & 31) + 32 * mt;
    const float* W = which ? w3 : w2;
    const float* p = W + o * 64 + 16 * t + 4 * gg;
    unsigned* d = &lds_w[(unsigned)((16 + which * 8 + F) * 64 + L) * 4u];
    d[0] = pk2(p[0], p[1]); d[1] = pk2(p[2], p[3]);
    d[2] = pk2(p[8], p[9]); d[3] = pk2(p[10], p[11]);
  }
  __syncthreads();

  const int lane = tid & 63;
  const int el = lane & 31;
  const int g = lane >> 5;
  const bf16x8* wfrag = (const bf16x8*)lds_w;

  const int wid = blockIdx.x * 4 + (tid >> 6);
  const int nw = gridDim.x * 4;

  for (int tile = wid; tile < (NE / 32); tile += nw) {
    const int e = tile * 32 + el;
    int vsrc = ei[e];
    int vtgt = ei[NE + e];
    vsrc = min(max(vsrc, 0), NN - 1);
    vtgt = min(max(vtgt, 0), NN - 1);
    const float wgt = ew[e];

    const float* xi = x + (size_t)vtgt * 64 + 8 * g;
    const float* xj = x + (size_t)vsrc * 64 + 8 * g;

    // ---- build m half-row: slots t=0..3 -> x_i chunks, t=4..7 -> ew*(x_j-x_i) ----
    float m[64];
    #pragma unroll
    for (int t = 0; t < 4; ++t) {
      float4 a = *(const float4*)(xi + 16 * t);
      float4 b = *(const float4*)(xi + 16 * t + 4);
      float4 c = *(const float4*)(xj + 16 * t);
      float4 d4 = *(const float4*)(xj + 16 * t + 4);
      m[8*t+0] = a.x; m[8*t+1] = a.y; m[8*t+2] = a.z; m[8*t+3] = a.w;
      m[8*t+4] = b.x; m[8*t+5] = b.y; m[8*t+6] = b.z; m[8*t+7] = b.w;
      m[32+8*t+0] = wgt * (c.x - a.x);  m[32+8*t+1] = wgt * (c.y - a.y);
      m[32+8*t+2] = wgt * (c.z - a.z);  m[32+8*t+3] = wgt * (c.w - a.w);
      m[32+8*t+4] = wgt * (d4.x - b.x); m[32+8*t+5] = wgt * (d4.y - b.y);
      m[32+8*t+6] = wgt * (d4.z - b.z); m[32+8*t+7] = wgt * (d4.w - b.w);
    }

    // ---- LN1 stats over 128 (two lanes per edge) ----
    float sum = 0.f, ssq = 0.f;
    #pragma unroll
    for (int i = 0; i < 64; ++i) { sum += m[i]; ssq += m[i] * m[i]; }
    sum += __shfl_xor(sum, 32);
    ssq += __shfl_xor(ssq, 32);
    const float mean1 = sum * (1.f / 128.f);
    const float rstd1 = rsqrtf(ssq * (1.f / 128.f) - mean1 * mean1 + 1e-5f);
    const float c01 = -mean1 * rstd1;

    // ---- normalize + affine + LeakyReLU + pack B1 frags ----
    U4 B1[8];
    #pragma unroll
    for (int t = 0; t < 8; ++t) {
      const int kb = (t < 4) ? (16 * t + 8 * g) : (64 + 16 * (t - 4) + 8 * g);
      float4 ga = *(const float4*)(g1 + kb);
      float4 gb = *(const float4*)(g1 + kb + 4);
      float4 ba = *(const float4*)(b1 + kb);
      float4 bb = *(const float4*)(b1 + kb + 4);
      float ggv[8] = {ga.x, ga.y, ga.z, ga.w, gb.x, gb.y, gb.z, gb.w};
      float bbv[8] = {ba.x, ba.y, ba.z, ba.w, bb.x, bb.y, bb.z, bb.w};
      float h[8];
      #pragma unroll
      for (int j = 0; j < 8; ++j) {
        float v = fmaf(m[8 * t + j], rstd1, c01);
        v = fmaf(v, ggv[j], bbv[j]);
        h[j] = v > 0.f ? v : 0.2f * v;
      }
      B1[t].u[0] = pk2(h[0], h[1]); B1[t].u[1] = pk2(h[2], h[3]);
      B1[t].u[2] = pk2(h[4], h[5]); B1[t].u[3] = pk2(h[6], h[7]);
    }

    // ---- stage 1: C' = w1 @ h1^T  (64x32) ----
    f32x16 C0, C1;
    #pragma unroll
    for (int i = 0; i < 16; ++i) { C0[i] = 0.f; C1[i] = 0.f; }
    #pragma unroll
    for (int t = 0; t < 8; ++t) {
      C0 = __builtin_amdgcn_mfma_f32_32x32x16_bf16(wfrag[(2 * t + 0) * 64 + lane], B1[t].v, C0, 0, 0, 0);
      C1 = __builtin_amdgcn_mfma_f32_32x32x16_bf16(wfrag[(2 * t + 1) * 64 + lane], B1[t].v, C1, 0, 0, 0);
    }

    // ---- LN2 (+affine+act) -> B2 frags ----
    float s2 = 0.f, q2 = 0.f;
    #pragma unroll
    for (int i = 0; i < 16; ++i) {
      s2 += C0[i] + C1[i];
      q2 += C0[i] * C0[i] + C1[i] * C1[i];
    }
    s2 += __shfl_xor(s2, 32); q2 += __shfl_xor(q2, 32);
    const float mean2 = s2 * (1.f / 64.f);
    const float rstd2 = rsqrtf(q2 * (1.f / 64.f) - mean2 * mean2 + 1e-5f);
    const float c02 = -mean2 * rstd2;

    float h2[32];
    #pragma unroll
    for (int mt = 0; mt < 2; ++mt) {
      #pragma unroll
      for (int q = 0; q < 4; ++q) {
        const int f0 = 32 * mt + 8 * q + 4 * g;
        float4 gg4 = *(const float4*)(g2 + f0);
        float4 bb4 = *(const float4*)(b2 + f0);
        float ggv[4] = {gg4.x, gg4.y, gg4.z, gg4.w};
        float bbv[4] = {bb4.x, bb4.y, bb4.z, bb4.w};
        #pragma unroll
        for (int r = 0; r < 4; ++r) {
          float v = mt ? C1[4 * q + r] : C0[4 * q + r];
          v = fmaf(v, rstd2, c02);
          v = fmaf(v, ggv[r], bbv[r]);
          h2[mt * 16 + 4 * q + r] = v > 0.f ? v : 0.2f * v;
        }
      }
    }
    U4 B2[4];
    #pragma unroll
    for (int t2 = 0; t2 < 4; ++t2) {
      const int base = (t2 >> 1) * 16 + (t2 & 1) * 8;
      B2[t2].u[0] = pk2(h2[base + 0], h2[base + 1]);
      B2[t2].u[1] = pk2(h2[base + 2], h2[base + 3]);
      B2[t2].u[2] = pk2(h2[base + 4], h2[base + 5]);
      B2[t2].u[3] = pk2(h2[base + 6], h2[base + 7]);
    }

    // ---- stage 2 ----
    f32x16 D0, D1;
    #pragma unroll
    for (int i = 0; i < 16; ++i) { D0[i] = 0.f; D1[i] = 0.f; }
    #pragma unroll
    for (int t2 = 0; t2 < 4; ++t2) {
      D0 = __builtin_amdgcn_mfma_f32_32x32x16_bf16(wfrag[(16 + 2 * t2 + 0) * 64 + lane], B2[t2].v, D0, 0, 0, 0);
      D1 = __builtin_amdgcn_mfma_f32_32x32x16_bf16(wfrag[(16 + 2 * t2 + 1) * 64 + lane], B2[t2].v, D1, 0, 0, 0);
    }

    // ---- LN3 (+affine+act) -> B3 frags ----
    float s3 = 0.f, q3 = 0.f;
    #pragma unroll
    for (int i = 0; i < 16; ++i) {
      s3 += D0[i] + D1[i];
      q3 += D0[i] * D0[i] + D1[i] * D1[i];
    }
    s3 += __shfl_xor(s3, 32); q3 += __shfl_xor(q3, 32);
    const float mean3 = s3 * (1.f / 64.f);
    const float rstd3 = rsqrtf(q3 * (1.f / 64.f) - mean3 * mean3 + 1e-5f);
    const float c03 = -mean3 * rstd3;

    float h3[32];
    #pragma unroll
    for (int mt = 0; mt < 2; ++mt) {
      #pragma unroll
      for (int q = 0; q < 4; ++q) {
        const int f0 = 32 * mt + 8 * q + 4 * g;
        float4 gg4 = *(const float4*)(g3 + f0);
        float4 bb4 = *(const float4*)(b3 + f0);
        float ggv[4] = {gg4.x, gg4.y, gg4.z, gg4.w};
        float bbv[4] = {bb4.x, bb4.y, bb4.z, bb4.w};
        #pragma unroll
        for (int r = 0; r < 4; ++r) {
          float v = mt ? D1[4 * q + r] : D0[4 * q + r];
          v = fmaf(v, rstd3, c03);
          v = fmaf(v, ggv[r], bbv[r]);
          h3[mt * 16 + 4 * q + r] = v > 0.f ? v : 0.2f * v;
        }
      }
    }
    U4 B3[4];
    #pragma unroll
    for (int t2 = 0; t2 < 4; ++t2) {
      const int base = (t2 >> 1) * 16 + (t2 & 1) * 8;
      B3[t2].u[0] = pk2(h3[base + 0], h3[base + 1]);
      B3[t2].u[1] = pk2(h3[base + 2], h3[base + 3]);
      B3[t2].u[2] = pk2(h3[base + 4], h3[base + 5]);
      B3[t2].u[3] = pk2(h3[base + 6], h3[base + 7]);
    }

    // ---- stage 3 ----
    f32x16 F0, F1;
    #pragma unroll
    for (int i = 0; i < 16; ++i) { F0[i] = 0.f; F1[i] = 0.f; }
    #pragma unroll
    for (int t2 = 0; t2 < 4; ++t2) {
      F0 = __builtin_amdgcn_mfma_f32_32x32x16_bf16(wfrag[(24 + 2 * t2 + 0) * 64 + lane], B3[t2].v, F0, 0, 0, 0);
      F1 = __builtin_amdgcn_mfma_f32_32x32x16_bf16(wfrag[(24 + 2 * t2 + 1) * 64 + lane], B3[t2].v, F1, 0, 0, 0);
    }

    if (mbuf) {
      // ---- two-pass epilogue: store edge row as bf16 to m buffer ----
      // lane holds feature f = 8q + 4g + 32mt + {0..3} for q=0..3, mt=0..1
      unsigned short* row = mbuf + (size_t)e * 64;
      #pragma unroll
      for (int mt = 0; mt < 2; ++mt) {
        #pragma unroll
        for (int q = 0; q < 4; ++q) {
          const int f0 = 8 * q + 4 * g + 32 * mt;
          float v0 = mt ? F1[4 * q + 0] : F0[4 * q + 0];
          float v1 = mt ? F1[4 * q + 1] : F0[4 * q + 1];
          float v2 = mt ? F1[4 * q + 2] : F0[4 * q + 2];
          float v3 = mt ? F1[4 * q + 3] : F0[4 * q + 3];
          uint2 pk; pk.x = pk2(v0, v1); pk.y = pk2(v2, v3);
          *(uint2*)(row + f0) = pk;
        }
      }
    } else {
      // ---- fallback epilogue: atomic max scatter (monotone key encoding) ----
      unsigned* ap = agg + (size_t)vtgt * 64;
      #pragma unroll
      for (int mt = 0; mt < 2; ++mt) {
        #pragma unroll
        for (int reg = 0; reg < 16; ++reg) {
          const int f = (reg & 3) + 8 * (reg >> 2) + 4 * g + 32 * mt;
          float v = mt ? F1[reg] : F0[reg];
          unsigned u = __float_as_uint(v);
          unsigned key = (u & 0x80000000u) ? ~u : (u | 0x80000000u);
          atomicMax(ap + f, key);
        }
      }
    }
  }
}

// ---- pass 3: per-node gather max + residual ----
extern "C" __global__ void __launch_bounds__(256)
gather_max_kernel(const float* __restrict__ x, const unsigned short* __restrict__ mbuf,
                  const unsigned* __restrict__ cnt, const unsigned* __restrict__ bucket,
                  float* __restrict__ out) {
  const int node = blockIdx.x * 4 + (threadIdx.x >> 6);
  const int lane = threadIdx.x & 63;
  if (node >= NN) return;

  unsigned deg = cnt[node];
  if (deg > 64u) deg = 64u;
  const unsigned evec = (lane < (int)deg) ? bucket[((unsigned)node << 6) + lane] : 0u;

  float maxv = -INFINITY;
  unsigned k = 0;
  for (; k + 4 <= deg; k += 4) {
    const unsigned e0 = (unsigned)__shfl((int)evec, (int)(k + 0));
    const unsigned e1 = (unsigned)__shfl((int)evec, (int)(k + 1));
    const unsigned e2 = (unsigned)__shfl((int)evec, (int)(k + 2));
    const unsigned e3 = (unsigned)__shfl((int)evec, (int)(k + 3));
    const float v0 = __uint_as_float((unsigned)mbuf[(size_t)e0 * 64 + lane] << 16);
    const float v1 = __uint_as_float((unsigned)mbuf[(size_t)e1 * 64 + lane] << 16);
    const float v2 = __uint_as_float((unsigned)mbuf[(size_t)e2 * 64 + lane] << 16);
    const float v3 = __uint_as_float((unsigned)mbuf[(size_t)e3 * 64 + lane] << 16);
    maxv = fmaxf(maxv, fmaxf(fmaxf(v0, v1), fmaxf(v2, v3)));
  }
  for (; k < deg; ++k) {
    const unsigned e = (unsigned)__shfl((int)evec, (int)k);
    maxv = fmaxf(maxv, __uint_as_float((unsigned)mbuf[(size_t)e * 64 + lane] << 16));
  }
  if (deg == 0u) maxv = 0.f;  // isolated node: segment_max -> -inf -> 0

  const size_t oi = (size_t)node * 64 + lane;
  out[oi] = maxv + x[oi];
}

// ---- fallback finalize (atomic path) ----
extern "C" __global__ void __launch_bounds__(256)
finalize_kernel(const float* __restrict__ x, unsigned* __restrict__ out) {
  const int i = blockIdx.x * 256 + threadIdx.x;
  if (i < NN * 64) {
    const unsigned key = out[i];
    const unsigned u = (key & 0x80000000u) ? (key & 0x7FFFFFFFu) : ~key;
    float v = __uint_as_float(u);
    if (((u >> 23) & 0xFFu) == 0xFFu) v = 0.f;  // sentinel / non-finite -> 0
    ((float*)out)[i] = v + x[i];
  }
}

extern "C" void kernel_launch(void* const* d_in, const int* in_sizes, int n_in,
                              void* d_out, int out_size, void* d_ws, size_t ws_size,
                              hipStream_t stream) {
  (void)in_sizes; (void)n_in; (void)out_size;
  const float* x  = (const float*)d_in[0];
  const float* ew = (const float*)d_in[1];
  const int*   ei = (const int*)d_in[2];
  const float* w1 = (const float*)d_in[3];
  const float* w2 = (const float*)d_in[4];
  const float* w3 = (const float*)d_in[5];
  const float* g1 = (const float*)d_in[6];
  const float* b1 = (const float*)d_in[7];
  const float* g2 = (const float*)d_in[8];
  const float* b2 = (const float*)d_in[9];
  const float* g3 = (const float*)d_in[10];
  const float* b3 = (const float*)d_in[11];

  if (ws_size >= WS_NEEDED) {
    // ---- two-pass path: bucket build -> edge MLP -> gather max ----
    unsigned* cnt = (unsigned*)((char*)d_ws + CNT_OFF);
    unsigned* bucket = (unsigned*)((char*)d_ws + BUCKET_OFF);
    unsigned short* mbuf = (unsigned short*)((char*)d_ws + M_OFF);

    hipMemsetAsync(cnt, 0, (size_t)NN * sizeof(unsigned), stream);
    scatter_kernel<<<(NE + 255) / 256, 256, 0, stream>>>(ei, cnt, bucket);
    edge_mlp_kernel<<<1024, 256, 0, stream>>>(x, ew, ei, w1, w2, w3,
                                              g1, b1, g2, b2, g3, b3,
                                              nullptr, mbuf);
    gather_max_kernel<<<(NN + 3) / 4, 256, 0, stream>>>(x, mbuf, cnt, bucket,
                                                        (float*)d_out);
  } else {
    // ---- fallback: atomic path ----
    unsigned* agg = (unsigned*)d_out;
    hipMemsetAsync(d_out, 0, (size_t)NN * 64 * sizeof(float), stream);
    edge_mlp_kernel<<<1024, 256, 0, stream>>>(x, ew, ei, w1, w2, w3,
                                              g1, b1, g2, b2, g3, b3,
                                              agg, nullptr);
    finalize_kernel<<<(NN * 64 + 255) / 256, 256, 0, stream>>>(x, (unsigned*)d_out);
  }
}

// Round 4
// 342.890 us; speedup vs baseline: 3.4143x; 1.0515x over previous
//
#include <hip/hip_runtime.h>

#define NN 50000
#define NE 800000

// workspace layout (CSR two-pass path)
#define CNT_OFF   0u             // 50000 u32 counters (200 KB)
#define BASE_OFF  (1u << 18)     // 50001 u32 CSR bases (200 KB)
#define SLOT_OFF  (1u << 19)     // 800000 u32 per-edge slot (3.2 MB)
#define M_OFF     (1u << 22)     // 800000*64 bf16 edge outputs (102.4 MB)
#define WS_NEEDED ((size_t)(1u << 22) + (size_t)NE * 64u * 2u)

typedef __bf16 bf16x8 __attribute__((ext_vector_type(8)));
typedef float f32x16 __attribute__((ext_vector_type(16)));

union U4 { unsigned u[4]; __bf16 h[8]; bf16x8 v; };

// pack two f32 -> one u32 of 2 bf16 (compiler emits v_cvt_pk_bf16_f32)
__device__ __forceinline__ unsigned pkpair(float a, float b) {
  union { unsigned u; __bf16 h[2]; } r;
  r.h[0] = (__bf16)a; r.h[1] = (__bf16)b;
  return r.u;
}
__device__ __forceinline__ float bflo(unsigned u) { return __uint_as_float(u << 16); }
__device__ __forceinline__ float bfhi(unsigned u) { return __uint_as_float(u & 0xFFFF0000u); }

// ---- pass 1: count + slot assignment ----
extern "C" __global__ void __launch_bounds__(256)
scatter_kernel(const int* __restrict__ ei, unsigned* __restrict__ cnt,
               unsigned* __restrict__ slot) {
  const int e = blockIdx.x * 256 + threadIdx.x;
  if (e < NE) {
    int t = ei[NE + e];
    t = min(max(t, 0), NN - 1);
    slot[e] = atomicAdd(cnt + t, 1u);
  }
}

// ---- pass 1b: single-block exclusive scan of cnt -> base ----
extern "C" __global__ void __launch_bounds__(1024)
scan_kernel(const unsigned* __restrict__ cnt, unsigned* __restrict__ base) {
  __shared__ unsigned wsum[16];
  __shared__ unsigned carry;
  const int tid = threadIdx.x;
  const int wv = tid >> 6, ln = tid & 63;
  if (tid == 0) carry = 0;
  __syncthreads();
  for (int off = 0; off < NN; off += 1024) {
    const int i = off + tid;
    const unsigned v = (i < NN) ? cnt[i] : 0u;
    unsigned s = v;
    #pragma unroll
    for (int d = 1; d < 64; d <<= 1) {
      const unsigned t = __shfl_up(s, d);
      if (ln >= d) s += t;
    }
    if (ln == 63) wsum[wv] = s;
    __syncthreads();
    if (tid == 0) {
      unsigned run = carry;
      #pragma unroll
      for (int k = 0; k < 16; ++k) { const unsigned t = wsum[k]; wsum[k] = run; run += t; }
      carry = run;
    }
    __syncthreads();
    if (i < NN) base[i] = wsum[wv] + s - v;  // exclusive prefix
    __syncthreads();
  }
  if (tid == 0) base[NN] = carry;
}

// ---- pass 2: per-edge MLP (MFMA); epilogue = CSR bf16 store OR atomic fallback ----
extern "C" __global__ void __launch_bounds__(256)
edge_mlp_kernel(const float* __restrict__ x, const float* __restrict__ ew,
                const int* __restrict__ ei, const float* __restrict__ w1,
                const float* __restrict__ w2, const float* __restrict__ w3,
                const float* __restrict__ g1, const float* __restrict__ b1,
                const float* __restrict__ g2, const float* __restrict__ b2,
                const float* __restrict__ g3, const float* __restrict__ b3,
                const unsigned* __restrict__ basep, const unsigned* __restrict__ slot,
                unsigned* __restrict__ agg /* fallback */,
                unsigned short* __restrict__ mbuf /* CSR path */) {
  __shared__ unsigned lds_w[8192];  // 32 frags x 64 lanes x 16B = 32 KB
  const int tid = threadIdx.x;

  // ---- stage w1 (16 frags): slot j <-> k = 16t + 8g + j ----
  #pragma unroll 1
  for (int s = tid; s < 1024; s += 256) {
    const int F = s >> 6, L = s & 63;
    const int t = F >> 1, mt = F & 1;
    const int gg = L >> 5, o = (L & 31) + 32 * mt;
    const float* p = w1 + o * 128 + 16 * t + 8 * gg;
    unsigned* d = &lds_w[(unsigned)(F * 64 + L) * 4u];
    d[0] = pkpair(p[0], p[1]); d[1] = pkpair(p[2], p[3]);
    d[2] = pkpair(p[4], p[5]); d[3] = pkpair(p[6], p[7]);
  }
  // ---- stage w2/w3 (8 frags each): slot j <-> k = 16t + 4g + (j&3) + 8*(j>>2) ----
  #pragma unroll 1
  for (int s = tid; s < 1024; s += 256) {
    const int which = s >> 9, r = s & 511;
    const int F = r >> 6, L = r & 63;
    const int t = F >> 1, mt = F & 1;
    const int gg = L >> 5, o = (L & 31) + 32 * mt;
    const float* W = which ? w3 : w2;
    const float* p = W + o * 64 + 16 * t + 4 * gg;
    unsigned* d = &lds_w[(unsigned)((16 + which * 8 + F) * 64 + L) * 4u];
    d[0] = pkpair(p[0], p[1]); d[1] = pkpair(p[2], p[3]);
    d[2] = pkpair(p[8], p[9]); d[3] = pkpair(p[10], p[11]);
  }
  __syncthreads();

  const int lane = tid & 63;
  const int el = lane & 31;
  const int g = lane >> 5;
  const bf16x8* wfrag = (const bf16x8*)lds_w;

  const int wid = blockIdx.x * 4 + (tid >> 6);
  const int nw = gridDim.x * 4;

  for (int tile = wid; tile < (NE / 32); tile += nw) {
    // anti-LICM: keep affine-param loads inside the loop (L1-resident),
    // freeing ~100 VGPRs the compiler would otherwise hoist into.
    const float* g1p = g1; const float* b1p = b1;
    const float* g2p = g2; const float* b2p = b2;
    const float* g3p = g3; const float* b3p = b3;
    asm volatile("" : "+s"(g1p), "+s"(b1p), "+s"(g2p), "+s"(b2p), "+s"(g3p), "+s"(b3p));

    const int e = tile * 32 + el;
    int vsrc = ei[e];
    int vtgt = ei[NE + e];
    vsrc = min(max(vsrc, 0), NN - 1);
    vtgt = min(max(vtgt, 0), NN - 1);
    const float wgt = ew[e];

    const float* xi = x + (size_t)vtgt * 64 + 8 * g;
    const float* xj = x + (size_t)vsrc * 64 + 8 * g;

    // ---- build m half-row, packed bf16; f32 stats on the fly ----
    // mp[4t+p] (t<4): x_i pairs; mp[16+4t+p]: ew*(x_j-x_i) pairs
    unsigned mp[32];
    float sum = 0.f, ssq = 0.f;
    #pragma unroll
    for (int t = 0; t < 4; ++t) {
      float4 a = *(const float4*)(xi + 16 * t);
      float4 b = *(const float4*)(xi + 16 * t + 4);
      float4 c = *(const float4*)(xj + 16 * t);
      float4 d4 = *(const float4*)(xj + 16 * t + 4);
      float lo[8] = {a.x, a.y, a.z, a.w, b.x, b.y, b.z, b.w};
      float up[8] = {wgt * (c.x - a.x), wgt * (c.y - a.y), wgt * (c.z - a.z), wgt * (c.w - a.w),
                     wgt * (d4.x - b.x), wgt * (d4.y - b.y), wgt * (d4.z - b.z), wgt * (d4.w - b.w)};
      #pragma unroll
      for (int p = 0; p < 4; ++p) {
        mp[4 * t + p] = pkpair(lo[2 * p], lo[2 * p + 1]);
        mp[16 + 4 * t + p] = pkpair(up[2 * p], up[2 * p + 1]);
      }
      #pragma unroll
      for (int j = 0; j < 8; ++j) {
        sum += lo[j] + up[j];
        ssq += lo[j] * lo[j] + up[j] * up[j];
      }
    }

    sum += __shfl_xor(sum, 32);
    ssq += __shfl_xor(ssq, 32);
    const float mean1 = sum * (1.f / 128.f);
    const float rstd1 = rsqrtf(ssq * (1.f / 128.f) - mean1 * mean1 + 1e-5f);
    const float c01 = -mean1 * rstd1;

    // ---- normalize + affine + LeakyReLU -> B1 frags ----
    U4 B1[8];
    #pragma unroll
    for (int t = 0; t < 8; ++t) {
      const int kb = ((t < 4) ? 16 * t : 64 + 16 * (t - 4)) + 8 * g;
      float4 ga = *(const float4*)(g1p + kb);
      float4 gb = *(const float4*)(g1p + kb + 4);
      float4 ba = *(const float4*)(b1p + kb);
      float4 bb = *(const float4*)(b1p + kb + 4);
      float gv[8] = {ga.x, ga.y, ga.z, ga.w, gb.x, gb.y, gb.z, gb.w};
      float bv[8] = {ba.x, ba.y, ba.z, ba.w, bb.x, bb.y, bb.z, bb.w};
      #pragma unroll
      for (int p = 0; p < 4; ++p) {
        const unsigned u = mp[4 * t + p];
        float v0 = fmaf(bflo(u), rstd1, c01);
        float v1 = fmaf(bfhi(u), rstd1, c01);
        v0 = fmaf(v0, gv[2 * p], bv[2 * p]);
        v1 = fmaf(v1, gv[2 * p + 1], bv[2 * p + 1]);
        v0 = v0 > 0.f ? v0 : 0.2f * v0;
        v1 = v1 > 0.f ? v1 : 0.2f * v1;
        B1[t].h[2 * p] = (__bf16)v0;
        B1[t].h[2 * p + 1] = (__bf16)v1;
      }
    }

    // ---- stage 1: C' = w1 @ h1^T  (64x32) ----
    f32x16 C0, C1;
    #pragma unroll
    for (int i = 0; i < 16; ++i) { C0[i] = 0.f; C1[i] = 0.f; }
    #pragma unroll
    for (int t = 0; t < 8; ++t) {
      C0 = __builtin_amdgcn_mfma_f32_32x32x16_bf16(wfrag[(2 * t + 0) * 64 + lane], B1[t].v, C0, 0, 0, 0);
      C1 = __builtin_amdgcn_mfma_f32_32x32x16_bf16(wfrag[(2 * t + 1) * 64 + lane], B1[t].v, C1, 0, 0, 0);
    }

    // ---- LN2 (+affine+act) -> B2 frags (direct from accumulators) ----
    float s2 = 0.f, q2 = 0.f;
    #pragma unroll
    for (int i = 0; i < 16; ++i) {
      s2 += C0[i] + C1[i];
      q2 += C0[i] * C0[i] + C1[i] * C1[i];
    }
    s2 += __shfl_xor(s2, 32); q2 += __shfl_xor(q2, 32);
    const float mean2 = s2 * (1.f / 64.f);
    const float rstd2 = rsqrtf(q2 * (1.f / 64.f) - mean2 * mean2 + 1e-5f);
    const float c02 = -mean2 * rstd2;

    U4 B2[4];
    #pragma unroll
    for (int t2 = 0; t2 < 4; ++t2) {
      const int kb = 16 * t2 + 4 * g;
      float4 gA = *(const float4*)(g2p + kb);
      float4 gB = *(const float4*)(g2p + kb + 8);
      float4 bA = *(const float4*)(b2p + kb);
      float4 bB = *(const float4*)(b2p + kb + 8);
      float gv[8] = {gA.x, gA.y, gA.z, gA.w, gB.x, gB.y, gB.z, gB.w};
      float bv[8] = {bA.x, bA.y, bA.z, bA.w, bB.x, bB.y, bB.z, bB.w};
      #pragma unroll
      for (int j = 0; j < 8; ++j) {
        const int reg = 4 * (2 * (t2 & 1) + (j >> 2)) + (j & 3);
        float v = (t2 >> 1) ? C1[reg] : C0[reg];
        v = fmaf(v, rstd2, c02);
        v = fmaf(v, gv[j], bv[j]);
        v = v > 0.f ? v : 0.2f * v;
        B2[t2].h[j] = (__bf16)v;
      }
    }

    // ---- stage 2 ----
    f32x16 D0, D1;
    #pragma unroll
    for (int i = 0; i < 16; ++i) { D0[i] = 0.f; D1[i] = 0.f; }
    #pragma unroll
    for (int t2 = 0; t2 < 4; ++t2) {
      D0 = __builtin_amdgcn_mfma_f32_32x32x16_bf16(wfrag[(16 + 2 * t2 + 0) * 64 + lane], B2[t2].v, D0, 0, 0, 0);
      D1 = __builtin_amdgcn_mfma_f32_32x32x16_bf16(wfrag[(16 + 2 * t2 + 1) * 64 + lane], B2[t2].v, D1, 0, 0, 0);
    }

    // ---- LN3 (+affine+act) -> B3 frags ----
    float s3 = 0.f, q3 = 0.f;
    #pragma unroll
    for (int i = 0; i < 16; ++i) {
      s3 += D0[i] + D1[i];
      q3 += D0[i] * D0[i] + D1[i] * D1[i];
    }
    s3 += __shfl_xor(s3, 32); q3 += __shfl_xor(q3, 32);
    const float mean3 = s3 * (1.f / 64.f);
    const float rstd3 = rsqrtf(q3 * (1.f / 64.f) - mean3 * mean3 + 1e-5f);
    const float c03 = -mean3 * rstd3;

    U4 B3[4];
    #pragma unroll
    for (int t2 = 0; t2 < 4; ++t2) {
      const int kb = 16 * t2 + 4 * g;
      float4 gA = *(const float4*)(g3p + kb);
      float4 gB = *(const float4*)(g3p + kb + 8);
      float4 bA = *(const float4*)(b3p + kb);
      float4 bB = *(const float4*)(b3p + kb + 8);
      float gv[8] = {gA.x, gA.y, gA.z, gA.w, gB.x, gB.y, gB.z, gB.w};
      float bv[8] = {bA.x, bA.y, bA.z, bA.w, bB.x, bB.y, bB.z, bB.w};
      #pragma unroll
      for (int j = 0; j < 8; ++j) {
        const int reg = 4 * (2 * (t2 & 1) + (j >> 2)) + (j & 3);
        float v = (t2 >> 1) ? D1[reg] : D0[reg];
        v = fmaf(v, rstd3, c03);
        v = fmaf(v, gv[j], bv[j]);
        v = v > 0.f ? v : 0.2f * v;
        B3[t2].h[j] = (__bf16)v;
      }
    }

    // ---- stage 3 ----
    f32x16 F0, F1;
    #pragma unroll
    for (int i = 0; i < 16; ++i) { F0[i] = 0.f; F1[i] = 0.f; }
    #pragma unroll
    for (int t2 = 0; t2 < 4; ++t2) {
      F0 = __builtin_amdgcn_mfma_f32_32x32x16_bf16(wfrag[(24 + 2 * t2 + 0) * 64 + lane], B3[t2].v, F0, 0, 0, 0);
      F1 = __builtin_amdgcn_mfma_f32_32x32x16_bf16(wfrag[(24 + 2 * t2 + 1) * 64 + lane], B3[t2].v, F1, 0, 0, 0);
    }

    if (mbuf) {
      // ---- CSR epilogue: store edge row at its bucket-sorted position ----
      const unsigned pos = basep[vtgt] + slot[e];
      unsigned short* row = mbuf + (size_t)pos * 64;
      #pragma unroll
      for (int mt = 0; mt < 2; ++mt) {
        #pragma unroll
        for (int q = 0; q < 4; ++q) {
          const int f0 = 8 * q + 4 * g + 32 * mt;
          uint2 pk;
          pk.x = mt ? pkpair(F1[4 * q + 0], F1[4 * q + 1]) : pkpair(F0[4 * q + 0], F0[4 * q + 1]);
          pk.y = mt ? pkpair(F1[4 * q + 2], F1[4 * q + 3]) : pkpair(F0[4 * q + 2], F0[4 * q + 3]);
          *(uint2*)(row + f0) = pk;
        }
      }
    } else {
      // ---- fallback epilogue: atomic max scatter (monotone key encoding) ----
      unsigned* ap = agg + (size_t)vtgt * 64;
      #pragma unroll
      for (int mt = 0; mt < 2; ++mt) {
        #pragma unroll
        for (int reg = 0; reg < 16; ++reg) {
          const int f = (reg & 3) + 8 * (reg >> 2) + 4 * g + 32 * mt;
          float v = mt ? F1[reg] : F0[reg];
          unsigned u = __float_as_uint(v);
          unsigned key = (u & 0x80000000u) ? ~u : (u | 0x80000000u);
          atomicMax(ap + f, key);
        }
      }
    }
  }
}

// ---- pass 3: per-node contiguous gather max + residual ----
extern "C" __global__ void __launch_bounds__(256)
gather_max_kernel(const float* __restrict__ x, const unsigned short* __restrict__ mbuf,
                  const unsigned* __restrict__ base, float* __restrict__ out) {
  const int node = blockIdx.x * 4 + (threadIdx.x >> 6);
  const int lane = threadIdx.x & 63;
  if (node >= NN) return;

  const unsigned b0 = base[node];
  const unsigned deg = base[node + 1] - b0;

  // lane reads ushort4 -> 4 features of row (chunk*4 + lane>>4); 4 rows/iter
  const unsigned short* p = mbuf + (size_t)b0 * 64 + lane * 4;
  const int krow = lane >> 4;
  float4 acc = {-INFINITY, -INFINITY, -INFINITY, -INFINITY};
  const int nch = ((int)deg + 3) >> 2;
  for (int c = 0; c < nch; ++c) {
    if (c * 4 + krow < (int)deg) {
      const ushort4 v = *(const ushort4*)(p + (size_t)c * 256);
      acc.x = fmaxf(acc.x, __uint_as_float((unsigned)v.x << 16));
      acc.y = fmaxf(acc.y, __uint_as_float((unsigned)v.y << 16));
      acc.z = fmaxf(acc.z, __uint_as_float((unsigned)v.z << 16));
      acc.w = fmaxf(acc.w, __uint_as_float((unsigned)v.w << 16));
    }
  }
  // combine the 4 row-groups (lanes L, L+16, L+32, L+48 share features)
  #pragma unroll
  for (int d = 16; d < 64; d <<= 1) {
    acc.x = fmaxf(acc.x, __shfl_xor(acc.x, d));
    acc.y = fmaxf(acc.y, __shfl_xor(acc.y, d));
    acc.z = fmaxf(acc.z, __shfl_xor(acc.z, d));
    acc.w = fmaxf(acc.w, __shfl_xor(acc.w, d));
  }
  if (lane < 16) {
    const size_t o = (size_t)node * 64 + lane * 4;
    const float4 xr = *(const float4*)(x + o);
    float4 r;
    r.x = (acc.x >= -3.0e38f ? acc.x : 0.f) + xr.x;
    r.y = (acc.y >= -3.0e38f ? acc.y : 0.f) + xr.y;
    r.z = (acc.z >= -3.0e38f ? acc.z : 0.f) + xr.z;
    r.w = (acc.w >= -3.0e38f ? acc.w : 0.f) + xr.w;
    *(float4*)(out + o) = r;
  }
}

// ---- fallback finalize (atomic path) ----
extern "C" __global__ void __launch_bounds__(256)
finalize_kernel(const float* __restrict__ x, unsigned* __restrict__ out) {
  const int i = blockIdx.x * 256 + threadIdx.x;
  if (i < NN * 64) {
    const unsigned key = out[i];
    const unsigned u = (key & 0x80000000u) ? (key & 0x7FFFFFFFu) : ~key;
    float v = __uint_as_float(u);
    if (((u >> 23) & 0xFFu) == 0xFFu) v = 0.f;  // sentinel / non-finite -> 0
    ((float*)out)[i] = v + x[i];
  }
}

extern "C" void kernel_launch(void* const* d_in, const int* in_sizes, int n_in,
                              void* d_out, int out_size, void* d_ws, size_t ws_size,
                              hipStream_t stream) {
  (void)in_sizes; (void)n_in; (void)out_size;
  const float* x  = (const float*)d_in[0];
  const float* ew = (const float*)d_in[1];
  const int*   ei = (const int*)d_in[2];
  const float* w1 = (const float*)d_in[3];
  const float* w2 = (const float*)d_in[4];
  const float* w3 = (const float*)d_in[5];
  const float* g1 = (const float*)d_in[6];
  const float* b1 = (const float*)d_in[7];
  const float* g2 = (const float*)d_in[8];
  const float* b2 = (const float*)d_in[9];
  const float* g3 = (const float*)d_in[10];
  const float* b3 = (const float*)d_in[11];

  if (ws_size >= WS_NEEDED) {
    // ---- CSR path: count/slot -> scan -> edge MLP (sorted store) -> gather max ----
    unsigned* cnt  = (unsigned*)((char*)d_ws + CNT_OFF);
    unsigned* base = (unsigned*)((char*)d_ws + BASE_OFF);
    unsigned* slot = (unsigned*)((char*)d_ws + SLOT_OFF);
    unsigned short* mbuf = (unsigned short*)((char*)d_ws + M_OFF);

    hipMemsetAsync(cnt, 0, (size_t)NN * sizeof(unsigned), stream);
    scatter_kernel<<<(NE + 255) / 256, 256, 0, stream>>>(ei, cnt, slot);
    scan_kernel<<<1, 1024, 0, stream>>>(cnt, base);
    edge_mlp_kernel<<<1024, 256, 0, stream>>>(x, ew, ei, w1, w2, w3,
                                              g1, b1, g2, b2, g3, b3,
                                              base, slot, nullptr, mbuf);
    gather_max_kernel<<<(NN + 3) / 4, 256, 0, stream>>>(x, mbuf, base, (float*)d_out);
  } else {
    // ---- fallback: atomic path ----
    unsigned* agg = (unsigned*)d_out;
    hipMemsetAsync(d_out, 0, (size_t)NN * 64 * sizeof(float), stream);
    edge_mlp_kernel<<<1024, 256, 0, stream>>>(x, ew, ei, w1, w2, w3,
                                              g1, b1, g2, b2, g3, b3,
                                              nullptr, nullptr, agg, nullptr);
    finalize_kernel<<<(NN * 64 + 255) / 256, 256, 0, stream>>>(x, (unsigned*)d_out);
  }
}

// Round 5
// 342.716 us; speedup vs baseline: 3.4161x; 1.0005x over previous
//
#include <hip/hip_runtime.h>

#define NN 50000
#define NE 800000
#define NT (NE / 32)

// workspace layout (CSR path) — stays within R4's proven footprint
#define CNT_OFF   0u        // 50000 u32 (200 KB)
#define CNT2_OFF  200704u   // 50000 u32 (200 KB)
#define BASE_OFF  401408u   // 50001 u32
#define PART_OFF  601856u   // 196 u32 block partials
#define EID_OFF   606208u   // 800000 u32 (3.2 MB), ends 3,806,208 < 4,194,304
#define M_OFF     (1u << 22)
#define WS_NEEDED ((size_t)(1u << 22) + (size_t)NE * 64u * 2u)
#define PB 196              // scan blocks: 196*256 = 50176 >= NN

typedef __bf16 bf16x8 __attribute__((ext_vector_type(8)));
typedef float f32x16 __attribute__((ext_vector_type(16)));

union U4 { unsigned u[4]; __bf16 h[8]; bf16x8 v; };

__device__ __forceinline__ unsigned pkpair(float a, float b) {
  union { unsigned u; __bf16 h[2]; } r;
  r.h[0] = (__bf16)a; r.h[1] = (__bf16)b;
  return r.u;
}
__device__ __forceinline__ float bflo(unsigned u) { return __uint_as_float(u << 16); }
__device__ __forceinline__ float bfhi(unsigned u) { return __uint_as_float(u & 0xFFFF0000u); }

// ---- pass 1: count edges per target ----
extern "C" __global__ void __launch_bounds__(256)
count_kernel(const int* __restrict__ ei, unsigned* __restrict__ cnt) {
  const int e = blockIdx.x * 256 + threadIdx.x;
  if (e < NE) {
    int t = ei[NE + e];
    t = min(max(t, 0), NN - 1);
    atomicAdd(cnt + t, 1u);
  }
}

// ---- pass 1b: hierarchical exclusive scan cnt -> base ----
extern "C" __global__ void __launch_bounds__(256)
scan_a_kernel(const unsigned* __restrict__ cnt, unsigned* __restrict__ partial) {
  __shared__ unsigned wsum[4];
  const int t = threadIdx.x, wv = t >> 6, ln = t & 63;
  const int i = blockIdx.x * 256 + t;
  unsigned v = (i < NN) ? cnt[i] : 0u;
  #pragma unroll
  for (int d = 1; d < 64; d <<= 1) v += (unsigned)__shfl_up((int)v, d) * (ln >= d ? 1u : 0u);
  if (ln == 63) wsum[wv] = v;
  __syncthreads();
  if (t == 0) partial[blockIdx.x] = wsum[0] + wsum[1] + wsum[2] + wsum[3];
}

extern "C" __global__ void __launch_bounds__(256)
scan_b_kernel(unsigned* __restrict__ partial, unsigned* __restrict__ base) {
  __shared__ unsigned wsum[4];
  const int t = threadIdx.x, wv = t >> 6, ln = t & 63;
  const unsigned v = (t < PB) ? partial[t] : 0u;
  unsigned s = v;
  #pragma unroll
  for (int d = 1; d < 64; d <<= 1) s += (unsigned)__shfl_up((int)s, d) * (ln >= d ? 1u : 0u);
  if (ln == 63) wsum[wv] = s;
  __syncthreads();
  unsigned woff = 0;
  #pragma unroll
  for (int k = 0; k < 4; ++k) woff += (k < wv) ? wsum[k] : 0u;
  if (t < PB) partial[t] = woff + s - v;  // exclusive
  if (t == 255) base[NN] = woff + s;      // total (== NE)
}

extern "C" __global__ void __launch_bounds__(256)
scan_c_kernel(const unsigned* __restrict__ cnt, const unsigned* __restrict__ partial,
              unsigned* __restrict__ base) {
  __shared__ unsigned wsum[4];
  const int t = threadIdx.x, wv = t >> 6, ln = t & 63;
  const int i = blockIdx.x * 256 + t;
  const unsigned v = (i < NN) ? cnt[i] : 0u;
  unsigned s = v;
  #pragma unroll
  for (int d = 1; d < 64; d <<= 1) s += (unsigned)__shfl_up((int)s, d) * (ln >= d ? 1u : 0u);
  if (ln == 63) wsum[wv] = s;
  __syncthreads();
  unsigned woff = 0;
  #pragma unroll
  for (int k = 0; k < 4; ++k) woff += (k < wv) ? wsum[k] : 0u;
  if (i < NN) base[i] = partial[blockIdx.x] + woff + s - v;
}

// ---- pass 1c: fill inverse permutation eid[pos] = e ----
extern "C" __global__ void __launch_bounds__(256)
fill_kernel(const int* __restrict__ ei, const unsigned* __restrict__ base,
            unsigned* __restrict__ cnt2, unsigned* __restrict__ eid) {
  const int e = blockIdx.x * 256 + threadIdx.x;
  if (e < NE) {
    int t = ei[NE + e];
    t = min(max(t, 0), NN - 1);
    const unsigned pos = base[t] + atomicAdd(cnt2 + t, 1u);
    eid[pos] = (unsigned)e;
  }
}

// ---- pass 2: per-edge MLP in CSR order; store row at position p ----
extern "C" __global__ void __launch_bounds__(256)
edge_mlp_kernel(const float* __restrict__ x, const float* __restrict__ ew,
                const int* __restrict__ ei, const float* __restrict__ w1,
                const float* __restrict__ w2, const float* __restrict__ w3,
                const float* __restrict__ g1, const float* __restrict__ b1,
                const float* __restrict__ g2, const float* __restrict__ b2,
                const float* __restrict__ g3, const float* __restrict__ b3,
                const unsigned* __restrict__ eid /* CSR order; null => identity */,
                unsigned* __restrict__ agg /* fallback */,
                unsigned short* __restrict__ mbuf /* CSR path */) {
  __shared__ unsigned lds_w[8192];  // 32 frags x 64 lanes x 16B = 32 KB
  const int tid = threadIdx.x;

  // ---- stage w1 (16 frags): slot j <-> k = 16t + 8g + j ----
  #pragma unroll 1
  for (int s = tid; s < 1024; s += 256) {
    const int F = s >> 6, L = s & 63;
    const int t = F >> 1, mt = F & 1;
    const int gg = L >> 5, o = (L & 31) + 32 * mt;
    const float* p = w1 + o * 128 + 16 * t + 8 * gg;
    unsigned* d = &lds_w[(unsigned)(F * 64 + L) * 4u];
    d[0] = pkpair(p[0], p[1]); d[1] = pkpair(p[2], p[3]);
    d[2] = pkpair(p[4], p[5]); d[3] = pkpair(p[6], p[7]);
  }
  // ---- stage w2/w3 (8 frags each): slot j <-> k = 16t + 4g + (j&3) + 8*(j>>2) ----
  #pragma unroll 1
  for (int s = tid; s < 1024; s += 256) {
    const int which = s >> 9, r = s & 511;
    const int F = r >> 6, L = r & 63;
    const int t = F >> 1, mt = F & 1;
    const int gg = L >> 5, o = (L & 31) + 32 * mt;
    const float* W = which ? w3 : w2;
    const float* p = W + o * 64 + 16 * t + 4 * gg;
    unsigned* d = &lds_w[(unsigned)((16 + which * 8 + F) * 64 + L) * 4u];
    d[0] = pkpair(p[0], p[1]); d[1] = pkpair(p[2], p[3]);
    d[2] = pkpair(p[8], p[9]); d[3] = pkpair(p[10], p[11]);
  }
  __syncthreads();

  const int lane = tid & 63;
  const int el = lane & 31;
  const int g = lane >> 5;
  const bf16x8* wfrag = (const bf16x8*)lds_w;

  const int wid = blockIdx.x * 4 + (tid >> 6);
  const int nw = gridDim.x * 4;

  // ---- index prefetch (one tile ahead) ----
  int tile = wid;
  int pe = 0, pvs = 0, pvt = 0; float pw = 0.f;
  if (tile < NT) {
    const int p0 = tile * 32 + el;
    pe = eid ? (int)eid[p0] : p0;
    pvs = min(max(ei[pe], 0), NN - 1);
    pvt = min(max(ei[NE + pe], 0), NN - 1);
    pw = ew[pe];
  }

  while (tile < NT) {
    const float* g1p = g1; const float* b1p = b1;
    const float* g2p = g2; const float* b2p = b2;
    const float* g3p = g3; const float* b3p = b3;
    asm volatile("" : "+s"(g1p), "+s"(b1p), "+s"(g2p), "+s"(b2p), "+s"(g3p), "+s"(b3p));

    const int p = tile * 32 + el;
    const int e = pe, vsrc = pvs, vtgt = pvt;
    const float wgt = pw;

    const float* xi = x + (size_t)vtgt * 64 + 8 * g;
    const float* xj = x + (size_t)vsrc * 64 + 8 * g;

    // ---- build m half-row, packed bf16; f32 stats on the fly ----
    unsigned mp[32];
    float sum = 0.f, ssq = 0.f;
    #pragma unroll
    for (int t = 0; t < 4; ++t) {
      float4 a = *(const float4*)(xi + 16 * t);
      float4 b = *(const float4*)(xi + 16 * t + 4);
      float4 c = *(const float4*)(xj + 16 * t);
      float4 d4 = *(const float4*)(xj + 16 * t + 4);
      float lo[8] = {a.x, a.y, a.z, a.w, b.x, b.y, b.z, b.w};
      float up[8] = {wgt * (c.x - a.x), wgt * (c.y - a.y), wgt * (c.z - a.z), wgt * (c.w - a.w),
                     wgt * (d4.x - b.x), wgt * (d4.y - b.y), wgt * (d4.z - b.z), wgt * (d4.w - b.w)};
      #pragma unroll
      for (int pp = 0; pp < 4; ++pp) {
        mp[4 * t + pp] = pkpair(lo[2 * pp], lo[2 * pp + 1]);
        mp[16 + 4 * t + pp] = pkpair(up[2 * pp], up[2 * pp + 1]);
      }
      #pragma unroll
      for (int j = 0; j < 8; ++j) {
        sum += lo[j] + up[j];
        ssq += lo[j] * lo[j] + up[j] * up[j];
      }
    }

    // ---- prefetch indices for next tile (overlaps with LN/MFMA below) ----
    const int ntile = tile + nw;
    if (ntile < NT) {
      const int pn = ntile * 32 + el;
      pe = eid ? (int)eid[pn] : pn;
      pvs = min(max(ei[pe], 0), NN - 1);
      pvt = min(max(ei[NE + pe], 0), NN - 1);
      pw = ew[pe];
    }

    sum += __shfl_xor(sum, 32);
    ssq += __shfl_xor(ssq, 32);
    const float mean1 = sum * (1.f / 128.f);
    const float rstd1 = rsqrtf(ssq * (1.f / 128.f) - mean1 * mean1 + 1e-5f);
    const float c01 = -mean1 * rstd1;

    // ---- LN1 affine + LeakyReLU -> B1 frags ----
    U4 B1[8];
    #pragma unroll
    for (int t = 0; t < 8; ++t) {
      const int kb = ((t < 4) ? 16 * t : 64 + 16 * (t - 4)) + 8 * g;
      float4 ga = *(const float4*)(g1p + kb);
      float4 gb = *(const float4*)(g1p + kb + 4);
      float4 ba = *(const float4*)(b1p + kb);
      float4 bb = *(const float4*)(b1p + kb + 4);
      float gv[8] = {ga.x, ga.y, ga.z, ga.w, gb.x, gb.y, gb.z, gb.w};
      float bv[8] = {ba.x, ba.y, ba.z, ba.w, bb.x, bb.y, bb.z, bb.w};
      #pragma unroll
      for (int pp = 0; pp < 4; ++pp) {
        const unsigned u = mp[4 * t + pp];
        float v0 = fmaf(bflo(u), rstd1, c01);
        float v1 = fmaf(bfhi(u), rstd1, c01);
        v0 = fmaf(v0, gv[2 * pp], bv[2 * pp]);
        v1 = fmaf(v1, gv[2 * pp + 1], bv[2 * pp + 1]);
        v0 = v0 > 0.f ? v0 : 0.2f * v0;
        v1 = v1 > 0.f ? v1 : 0.2f * v1;
        B1[t].h[2 * pp] = (__bf16)v0;
        B1[t].h[2 * pp + 1] = (__bf16)v1;
      }
    }

    // ---- stage 1 ----
    f32x16 C0, C1;
    #pragma unroll
    for (int i = 0; i < 16; ++i) { C0[i] = 0.f; C1[i] = 0.f; }
    #pragma unroll
    for (int t = 0; t < 8; ++t) {
      C0 = __builtin_amdgcn_mfma_f32_32x32x16_bf16(wfrag[(2 * t + 0) * 64 + lane], B1[t].v, C0, 0, 0, 0);
      C1 = __builtin_amdgcn_mfma_f32_32x32x16_bf16(wfrag[(2 * t + 1) * 64 + lane], B1[t].v, C1, 0, 0, 0);
    }

    // ---- LN2 -> B2 ----
    float s2 = 0.f, q2 = 0.f;
    #pragma unroll
    for (int i = 0; i < 16; ++i) {
      s2 += C0[i] + C1[i];
      q2 += C0[i] * C0[i] + C1[i] * C1[i];
    }
    s2 += __shfl_xor(s2, 32); q2 += __shfl_xor(q2, 32);
    const float mean2 = s2 * (1.f / 64.f);
    const float rstd2 = rsqrtf(q2 * (1.f / 64.f) - mean2 * mean2 + 1e-5f);
    const float c02 = -mean2 * rstd2;

    U4 B2[4];
    #pragma unroll
    for (int t2 = 0; t2 < 4; ++t2) {
      const int kb = 16 * t2 + 4 * g;
      float4 gA = *(const float4*)(g2p + kb);
      float4 gB = *(const float4*)(g2p + kb + 8);
      float4 bA = *(const float4*)(b2p + kb);
      float4 bB = *(const float4*)(b2p + kb + 8);
      float gv[8] = {gA.x, gA.y, gA.z, gA.w, gB.x, gB.y, gB.z, gB.w};
      float bv[8] = {bA.x, bA.y, bA.z, bA.w, bB.x, bB.y, bB.z, bB.w};
      #pragma unroll
      for (int j = 0; j < 8; ++j) {
        const int reg = 4 * (2 * (t2 & 1) + (j >> 2)) + (j & 3);
        float v = (t2 >> 1) ? C1[reg] : C0[reg];
        v = fmaf(v, rstd2, c02);
        v = fmaf(v, gv[j], bv[j]);
        v = v > 0.f ? v : 0.2f * v;
        B2[t2].h[j] = (__bf16)v;
      }
    }

    // ---- stage 2 ----
    f32x16 D0, D1;
    #pragma unroll
    for (int i = 0; i < 16; ++i) { D0[i] = 0.f; D1[i] = 0.f; }
    #pragma unroll
    for (int t2 = 0; t2 < 4; ++t2) {
      D0 = __builtin_amdgcn_mfma_f32_32x32x16_bf16(wfrag[(16 + 2 * t2 + 0) * 64 + lane], B2[t2].v, D0, 0, 0, 0);
      D1 = __builtin_amdgcn_mfma_f32_32x32x16_bf16(wfrag[(16 + 2 * t2 + 1) * 64 + lane], B2[t2].v, D1, 0, 0, 0);
    }

    // ---- LN3 -> B3 ----
    float s3 = 0.f, q3 = 0.f;
    #pragma unroll
    for (int i = 0; i < 16; ++i) {
      s3 += D0[i] + D1[i];
      q3 += D0[i] * D0[i] + D1[i] * D1[i];
    }
    s3 += __shfl_xor(s3, 32); q3 += __shfl_xor(q3, 32);
    const float mean3 = s3 * (1.f / 64.f);
    const float rstd3 = rsqrtf(q3 * (1.f / 64.f) - mean3 * mean3 + 1e-5f);
    const float c03 = -mean3 * rstd3;

    U4 B3[4];
    #pragma unroll
    for (int t2 = 0; t2 < 4; ++t2) {
      const int kb = 16 * t2 + 4 * g;
      float4 gA = *(const float4*)(g3p + kb);
      float4 gB = *(const float4*)(g3p + kb + 8);
      float4 bA = *(const float4*)(b3p + kb);
      float4 bB = *(const float4*)(b3p + kb + 8);
      float gv[8] = {gA.x, gA.y, gA.z, gA.w, gB.x, gB.y, gB.z, gB.w};
      float bv[8] = {bA.x, bA.y, bA.z, bA.w, bB.x, bB.y, bB.z, bB.w};
      #pragma unroll
      for (int j = 0; j < 8; ++j) {
        const int reg = 4 * (2 * (t2 & 1) + (j >> 2)) + (j & 3);
        float v = (t2 >> 1) ? D1[reg] : D0[reg];
        v = fmaf(v, rstd3, c03);
        v = fmaf(v, gv[j], bv[j]);
        v = v > 0.f ? v : 0.2f * v;
        B3[t2].h[j] = (__bf16)v;
      }
    }

    // ---- stage 3 ----
    f32x16 F0, F1;
    #pragma unroll
    for (int i = 0; i < 16; ++i) { F0[i] = 0.f; F1[i] = 0.f; }
    #pragma unroll
    for (int t2 = 0; t2 < 4; ++t2) {
      F0 = __builtin_amdgcn_mfma_f32_32x32x16_bf16(wfrag[(24 + 2 * t2 + 0) * 64 + lane], B3[t2].v, F0, 0, 0, 0);
      F1 = __builtin_amdgcn_mfma_f32_32x32x16_bf16(wfrag[(24 + 2 * t2 + 1) * 64 + lane], B3[t2].v, F1, 0, 0, 0);
    }

    if (mbuf) {
      // ---- CSR epilogue: row index IS the position p (contiguous stores) ----
      unsigned short* row = mbuf + (size_t)p * 64;
      #pragma unroll
      for (int mt = 0; mt < 2; ++mt) {
        #pragma unroll
        for (int q = 0; q < 4; ++q) {
          const int f0 = 8 * q + 4 * g + 32 * mt;
          uint2 pk;
          pk.x = mt ? pkpair(F1[4 * q + 0], F1[4 * q + 1]) : pkpair(F0[4 * q + 0], F0[4 * q + 1]);
          pk.y = mt ? pkpair(F1[4 * q + 2], F1[4 * q + 3]) : pkpair(F0[4 * q + 2], F0[4 * q + 3]);
          *(uint2*)(row + f0) = pk;
        }
      }
    } else {
      // ---- fallback epilogue: atomic max scatter ----
      unsigned* ap = agg + (size_t)vtgt * 64;
      #pragma unroll
      for (int mt = 0; mt < 2; ++mt) {
        #pragma unroll
        for (int reg = 0; reg < 16; ++reg) {
          const int f = (reg & 3) + 8 * (reg >> 2) + 4 * g + 32 * mt;
          float v = mt ? F1[reg] : F0[reg];
          unsigned u = __float_as_uint(v);
          unsigned key = (u & 0x80000000u) ? ~u : (u | 0x80000000u);
          atomicMax(ap + f, key);
        }
      }
    }

    tile = ntile;
  }
}

// ---- pass 3: per-node contiguous gather max + residual ----
extern "C" __global__ void __launch_bounds__(256)
gather_max_kernel(const float* __restrict__ x, const unsigned short* __restrict__ mbuf,
                  const unsigned* __restrict__ base, float* __restrict__ out) {
  const int node = blockIdx.x * 4 + (threadIdx.x >> 6);
  const int lane = threadIdx.x & 63;
  if (node >= NN) return;

  const unsigned b0 = base[node];
  const unsigned deg = base[node + 1] - b0;

  const unsigned short* p = mbuf + (size_t)b0 * 64 + lane * 4;
  const int krow = lane >> 4;
  float4 acc = {-INFINITY, -INFINITY, -INFINITY, -INFINITY};
  const int nch = ((int)deg + 3) >> 2;
  for (int c = 0; c < nch; ++c) {
    if (c * 4 + krow < (int)deg) {
      const ushort4 v = *(const ushort4*)(p + (size_t)c * 256);
      acc.x = fmaxf(acc.x, __uint_as_float((unsigned)v.x << 16));
      acc.y = fmaxf(acc.y, __uint_as_float((unsigned)v.y << 16));
      acc.z = fmaxf(acc.z, __uint_as_float((unsigned)v.z << 16));
      acc.w = fmaxf(acc.w, __uint_as_float((unsigned)v.w << 16));
    }
  }
  #pragma unroll
  for (int d = 16; d < 64; d <<= 1) {
    acc.x = fmaxf(acc.x, __shfl_xor(acc.x, d));
    acc.y = fmaxf(acc.y, __shfl_xor(acc.y, d));
    acc.z = fmaxf(acc.z, __shfl_xor(acc.z, d));
    acc.w = fmaxf(acc.w, __shfl_xor(acc.w, d));
  }
  if (lane < 16) {
    const size_t o = (size_t)node * 64 + lane * 4;
    const float4 xr = *(const float4*)(x + o);
    float4 r;
    r.x = (acc.x >= -3.0e38f ? acc.x : 0.f) + xr.x;
    r.y = (acc.y >= -3.0e38f ? acc.y : 0.f) + xr.y;
    r.z = (acc.z >= -3.0e38f ? acc.z : 0.f) + xr.z;
    r.w = (acc.w >= -3.0e38f ? acc.w : 0.f) + xr.w;
    *(float4*)(out + o) = r;
  }
}

// ---- fallback finalize (atomic path) ----
extern "C" __global__ void __launch_bounds__(256)
finalize_kernel(const float* __restrict__ x, unsigned* __restrict__ out) {
  const int i = blockIdx.x * 256 + threadIdx.x;
  if (i < NN * 64) {
    const unsigned key = out[i];
    const unsigned u = (key & 0x80000000u) ? (key & 0x7FFFFFFFu) : ~key;
    float v = __uint_as_float(u);
    if (((u >> 23) & 0xFFu) == 0xFFu) v = 0.f;
    ((float*)out)[i] = v + x[i];
  }
}

extern "C" void kernel_launch(void* const* d_in, const int* in_sizes, int n_in,
                              void* d_out, int out_size, void* d_ws, size_t ws_size,
                              hipStream_t stream) {
  (void)in_sizes; (void)n_in; (void)out_size;
  const float* x  = (const float*)d_in[0];
  const float* ew = (const float*)d_in[1];
  const int*   ei = (const int*)d_in[2];
  const float* w1 = (const float*)d_in[3];
  const float* w2 = (const float*)d_in[4];
  const float* w3 = (const float*)d_in[5];
  const float* g1 = (const float*)d_in[6];
  const float* b1 = (const float*)d_in[7];
  const float* g2 = (const float*)d_in[8];
  const float* b2 = (const float*)d_in[9];
  const float* g3 = (const float*)d_in[10];
  const float* b3 = (const float*)d_in[11];

  if (ws_size >= WS_NEEDED) {
    unsigned* cnt   = (unsigned*)((char*)d_ws + CNT_OFF);
    unsigned* cnt2  = (unsigned*)((char*)d_ws + CNT2_OFF);
    unsigned* base  = (unsigned*)((char*)d_ws + BASE_OFF);
    unsigned* part  = (unsigned*)((char*)d_ws + PART_OFF);
    unsigned* eid   = (unsigned*)((char*)d_ws + EID_OFF);
    unsigned short* mbuf = (unsigned short*)((char*)d_ws + M_OFF);

    hipMemsetAsync(d_ws, 0, BASE_OFF, stream);  // zero cnt + cnt2
    count_kernel<<<(NE + 255) / 256, 256, 0, stream>>>(ei, cnt);
    scan_a_kernel<<<PB, 256, 0, stream>>>(cnt, part);
    scan_b_kernel<<<1, 256, 0, stream>>>(part, base);
    scan_c_kernel<<<PB, 256, 0, stream>>>(cnt, part, base);
    fill_kernel<<<(NE + 255) / 256, 256, 0, stream>>>(ei, base, cnt2, eid);
    edge_mlp_kernel<<<2048, 256, 0, stream>>>(x, ew, ei, w1, w2, w3,
                                              g1, b1, g2, b2, g3, b3,
                                              eid, nullptr, mbuf);
    gather_max_kernel<<<(NN + 3) / 4, 256, 0, stream>>>(x, mbuf, base, (float*)d_out);
  } else {
    unsigned* agg = (unsigned*)d_out;
    hipMemsetAsync(d_out, 0, (size_t)NN * 64 * sizeof(float), stream);
    edge_mlp_kernel<<<1024, 256, 0, stream>>>(x, ew, ei, w1, w2, w3,
                                              g1, b1, g2, b2, g3, b3,
                                              nullptr, agg, nullptr);
    finalize_kernel<<<(NN * 64 + 255) / 256, 256, 0, stream>>>(x, (unsigned*)d_out);
  }
}